// Round 4
// baseline (51.865 us; speedup 1.0000x reference)
//
#include <hip/hip_runtime.h>

// Shapes fixed by the reference: B=1, S=4096, H=32, D=128, M=4096.
#define HH 32
#define DD 128
#define MM 4096
#define ROW_F4 1024          // H*D/4 float4 per token row
#define D_F4   32            // D/4 float4 per (h, m) row

typedef float v4f __attribute__((ext_vector_type(4)));

// One WAVE owns one (cache position m, tensor) row: 4096 floats = 16 v4f/lane.
// No LDS, no __syncthreads, no cross-wave coupling: loads -> in-register amax
// -> 6x shfl_xor -> quantize from registers -> stores. 2*M waves total.
__global__ __launch_bounds__(256)
void teleport_quant_kernel(const float* __restrict__ kin,
                           const float* __restrict__ vin,
                           const float* __restrict__ unc,
                           const float* __restrict__ kc_in,
                           const float* __restrict__ vc_in,
                           const float* __restrict__ ksc_in,
                           const float* __restrict__ vsc_in,
                           const int*   __restrict__ cur_pos,
                           float* __restrict__ kc_out,
                           float* __restrict__ vc_out,
                           float* __restrict__ ksc_out,
                           float* __restrict__ vsc_out,
                           int S)
{
    const int t    = threadIdx.x;
    const int lane = t & 63;
    const int w    = (blockIdx.x << 2) + (t >> 6);   // wave id in [0, 2*MM)
    const int m    = w >> 1;                          // cache position
    const int isV  = w & 1;                           // 0 = K, 1 = V

    // Inverse circular map: which token (if any) last wrote position m.
    int cp  = *cur_pos;
    int cpm = cp % MM; if (cpm < 0) cpm += MM;
    int s0  = m - cpm; if (s0 < 0) s0 += MM;
    const int s = (s0 < S) ? (s0 + MM * ((S - 1 - s0) / MM)) : -1;

    const v4f* cin  = reinterpret_cast<const v4f*>(isV ? vc_in : kc_in);
    v4f*       cout = reinterpret_cast<v4f*>(isV ? vc_out : kc_out);
    const float* sin_ = isV ? vsc_in  : ksc_in;
    float*       sout = isV ? vsc_out : ksc_out;

    if (s < 0) {
        // Position untouched this step: copy old cache row + scales through.
        #pragma unroll
        for (int c = 0; c < 16; ++c) {
            int f4 = c * 64 + lane;                     // 0..1023
            int o  = (f4 >> 5) * (MM * D_F4) + m * D_F4 + (f4 & 31);
            cout[o] = cin[o];
        }
        if (lane < HH) sout[lane * MM + m] = sin_[lane * MM + m];
        return;
    }

    // ---- quantize token s (one tensor) into cache position m ----
    const v4f* src = reinterpret_cast<const v4f*>(isV ? vin : kin)
                     + (size_t)s * ROW_F4;

    v4f a[16];
    float am = 0.0f;
    #pragma unroll
    for (int c = 0; c < 16; ++c) {
        a[c] = src[c * 64 + lane];
        am = fmaxf(am, fmaxf(fmaxf(fabsf(a[c].x), fabsf(a[c].y)),
                             fmaxf(fabsf(a[c].z), fabsf(a[c].w))));
    }

    // wave64 butterfly reduce
    #pragma unroll
    for (int off = 32; off > 0; off >>= 1)
        am = fmaxf(am, __shfl_xor(am, off, 64));

    const float u   = unc[s];
    const float div = (u > 0.1f) ? 224.0f : 448.0f;
    const float sc  = fmaxf(am / div, 1e-8f);
    const float r   = 1.0f / sc;    // correctly-rounded; <=1ulp vs per-elem div

    #pragma unroll
    for (int c = 0; c < 16; ++c) {
        int f4 = c * 64 + lane;
        int o  = (f4 >> 5) * (MM * D_F4) + m * D_F4 + (f4 & 31);
        v4f q;
        q.x = fminf(fmaxf(a[c].x * r, -448.0f), 448.0f);
        q.y = fminf(fmaxf(a[c].y * r, -448.0f), 448.0f);
        q.z = fminf(fmaxf(a[c].z * r, -448.0f), 448.0f);
        q.w = fminf(fmaxf(a[c].w * r, -448.0f), 448.0f);
        cout[o] = q;
    }

    if (lane < HH) sout[lane * MM + m] = sc;
}

extern "C" void kernel_launch(void* const* d_in, const int* in_sizes, int n_in,
                              void* d_out, int out_size, void* d_ws, size_t ws_size,
                              hipStream_t stream) {
    const float* kin = (const float*)d_in[0];
    const float* vin = (const float*)d_in[1];
    const float* unc = (const float*)d_in[2];
    const float* kc  = (const float*)d_in[3];
    const float* vc  = (const float*)d_in[4];
    const float* ksc = (const float*)d_in[5];
    const float* vsc = (const float*)d_in[6];
    const int*   cp  = (const int*)d_in[7];
    const int S = in_sizes[2];   // B*S with B=1

    float* out  = (float*)d_out;
    float* kco  = out;
    float* vco  = kco + (size_t)HH * MM * DD;
    float* ksco = vco + (size_t)HH * MM * DD;
    float* vsco = ksco + (size_t)HH * MM;

    // 2*MM waves, 4 waves per 256-thread block.
    teleport_quant_kernel<<<(2 * MM) / 4, 256, 0, stream>>>(
        kin, vin, unc, kc, vc, ksc, vsc, cp, kco, vco, ksco, vsco, S);
}

// Round 5
// 48.188 us; speedup vs baseline: 1.0763x; 1.0763x over previous
//
#include <hip/hip_runtime.h>

// Shapes fixed by the reference: B=1, S=4096, H=32, D=128, M=4096.
#define HH 32
#define DD 128
#define MM 4096
#define ROW_F4 1024          // H*D/4 float4 per token row
#define D_F4   32            // D/4 float4 per (h, m) row

typedef float v4f __attribute__((ext_vector_type(4)));

// One WAVE (= one 64-thread block) owns one (cache position m, tensor) row:
// 4096 floats = 16 v4f/lane. No LDS, no __syncthreads. Grid = 2*M blocks of
// 64 so the scheduler refills CUs at single-wave granularity (R4 showed 41%
// occupancy with an exactly-one-generation 4-wave-block grid -> convoy).
__global__ __launch_bounds__(64)
void teleport_quant_kernel(const float* __restrict__ kin,
                           const float* __restrict__ vin,
                           const float* __restrict__ unc,
                           const float* __restrict__ kc_in,
                           const float* __restrict__ vc_in,
                           const float* __restrict__ ksc_in,
                           const float* __restrict__ vsc_in,
                           const int*   __restrict__ cur_pos,
                           float* __restrict__ kc_out,
                           float* __restrict__ vc_out,
                           float* __restrict__ ksc_out,
                           float* __restrict__ vsc_out,
                           int S)
{
    const int lane = threadIdx.x;                    // 0..63
    const int w    = blockIdx.x;                     // wave id in [0, 2*MM)
    const int m    = w >> 1;                         // cache position
    const int isV  = w & 1;                          // 0 = K, 1 = V

    // Inverse circular map: which token (if any) last wrote position m.
    int cp  = *cur_pos;
    int cpm = cp % MM; if (cpm < 0) cpm += MM;
    int s0  = m - cpm; if (s0 < 0) s0 += MM;
    const int s = (s0 < S) ? (s0 + MM * ((S - 1 - s0) / MM)) : -1;

    const v4f* cin  = reinterpret_cast<const v4f*>(isV ? vc_in : kc_in);
    v4f*       cout = reinterpret_cast<v4f*>(isV ? vc_out : kc_out);
    const float* sin_ = isV ? vsc_in  : ksc_in;
    float*       sout = isV ? vsc_out : ksc_out;

    if (s < 0) {
        // Position untouched this step: copy old cache row + scales through.
        #pragma unroll
        for (int c = 0; c < 16; ++c) {
            int f4 = c * 64 + lane;                     // 0..1023
            int o  = (f4 >> 5) * (MM * D_F4) + m * D_F4 + (f4 & 31);
            cout[o] = cin[o];
        }
        if (lane < HH) sout[lane * MM + m] = sin_[lane * MM + m];
        return;
    }

    // ---- quantize token s (one tensor) into cache position m ----
    const v4f* src = reinterpret_cast<const v4f*>(isV ? vin : kin)
                     + (size_t)s * ROW_F4;

    v4f a[16];
    float am = 0.0f;
    #pragma unroll
    for (int c = 0; c < 16; ++c) {
        a[c] = src[c * 64 + lane];
        am = fmaxf(am, fmaxf(fmaxf(fabsf(a[c].x), fabsf(a[c].y)),
                             fmaxf(fabsf(a[c].z), fabsf(a[c].w))));
    }

    // wave64 butterfly reduce
    #pragma unroll
    for (int off = 32; off > 0; off >>= 1)
        am = fmaxf(am, __shfl_xor(am, off, 64));

    const float u   = unc[s];
    const float div = (u > 0.1f) ? 224.0f : 448.0f;
    const float sc  = fmaxf(am / div, 1e-8f);
    const float r   = 1.0f / sc;    // correctly-rounded; <=1ulp vs per-elem div

    #pragma unroll
    for (int c = 0; c < 16; ++c) {
        int f4 = c * 64 + lane;
        int o  = (f4 >> 5) * (MM * D_F4) + m * D_F4 + (f4 & 31);
        v4f q;
        q.x = fminf(fmaxf(a[c].x * r, -448.0f), 448.0f);
        q.y = fminf(fmaxf(a[c].y * r, -448.0f), 448.0f);
        q.z = fminf(fmaxf(a[c].z * r, -448.0f), 448.0f);
        q.w = fminf(fmaxf(a[c].w * r, -448.0f), 448.0f);
        cout[o] = q;
    }

    if (lane < HH) sout[lane * MM + m] = sc;
}

extern "C" void kernel_launch(void* const* d_in, const int* in_sizes, int n_in,
                              void* d_out, int out_size, void* d_ws, size_t ws_size,
                              hipStream_t stream) {
    const float* kin = (const float*)d_in[0];
    const float* vin = (const float*)d_in[1];
    const float* unc = (const float*)d_in[2];
    const float* kc  = (const float*)d_in[3];
    const float* vc  = (const float*)d_in[4];
    const float* ksc = (const float*)d_in[5];
    const float* vsc = (const float*)d_in[6];
    const int*   cp  = (const int*)d_in[7];
    const int S = in_sizes[2];   // B*S with B=1

    float* out  = (float*)d_out;
    float* kco  = out;
    float* vco  = kco + (size_t)HH * MM * DD;
    float* ksco = vco + (size_t)HH * MM * DD;
    float* vsco = ksco + (size_t)HH * MM;

    // 2*MM single-wave blocks.
    teleport_quant_kernel<<<2 * MM, 64, 0, stream>>>(
        kin, vin, unc, kc, vc, ksc, vsc, cp, kco, vco, ksco, vsco, S);
}